// Round 3
// baseline (641.665 us; speedup 1.0000x reference)
//
#include <hip/hip_runtime.h>
#include <hip/hip_bf16.h>
#include <cstdint>

#define NNODES 20000
#define NEDGES 640000
#define ETOT   (NEDGES + NNODES)
#define NGROUP 64
#define HC     256
#define DOUT   32
#define EMAX   1024

typedef short bf16x8 __attribute__((ext_vector_type(8)));  // 8 bf16 in 4 VGPRs (guide-verified)
typedef float f32x4  __attribute__((ext_vector_type(4)));

__device__ __forceinline__ float b2f(__hip_bfloat16 v) { return __bfloat162float(v); }

// float load robust to fp32 vs bf16 storage
__device__ __forceinline__ float ldf(const void* __restrict__ p, size_t i, int bf) {
    return bf ? __bfloat162float(((const __hip_bfloat16*)p)[i]) : ((const float*)p)[i];
}
// int load robust to int32 vs int64 storage (little-endian low word)
__device__ __forceinline__ int ld_idx(const int* __restrict__ p, size_t i, int f64) {
    return f64 ? p[2 * i] : p[i];
}

// ---------------- dtype probes ----------------
// flag[0]: edge_index is int64?   flag[1]: float arrays are bf16?
__global__ void k_probe(const unsigned int* __restrict__ xw, const int* __restrict__ ei,
                        int* __restrict__ flag) {
    if (threadIdx.x == 0 && blockIdx.x == 0) {
        int ones = 0;
        for (int i = 0; i < 256; i++) ones += (xw[i] >> 14) & 1;   // fp32 mantissa bit ~50%; bf16 exp MSB ~5%
        flag[1] = (ones < 64) ? 1 : 0;
        int zeros = 0;
        for (int i = 0; i < 256; i++) zeros += (ei[2 * i + 1] == 0) ? 1 : 0;  // int64 high words
        flag[0] = (zeros > 200) ? 1 : 0;
    }
}

// ---------------- CSR build over dst ----------------
__global__ void k_hist(const int* __restrict__ ei, int* __restrict__ deg,
                       const int* __restrict__ flag) {
    int i = blockIdx.x * blockDim.x + threadIdx.x;
    if (i >= ETOT) return;
    int f = flag[0];
    int d = (i < NEDGES) ? ld_idx(ei, (size_t)NEDGES + i, f) : (i - NEDGES);
    atomicAdd(&deg[d], 1);
}

__global__ void k_scan(const int* __restrict__ deg, int* __restrict__ off, int* __restrict__ cur) {
    __shared__ int part[512];
    int t = threadIdx.x;
    const int chunk = (NNODES + 511) / 512;  // 40
    int s = t * chunk, e = min(s + chunk, NNODES);
    int sum = 0;
    for (int i = s; i < e; i++) sum += deg[i];
    part[t] = sum;
    __syncthreads();
    if (t == 0) {
        int acc = 0;
        for (int i = 0; i < 512; i++) { int v = part[i]; part[i] = acc; acc += v; }
    }
    __syncthreads();
    int run = part[t];
    for (int i = s; i < e; i++) { off[i] = run; cur[i] = run; run += deg[i]; }
    if (t == 511) off[NNODES] = run;  // == ETOT
}

__global__ void k_scatter(const int* __restrict__ ei, int* __restrict__ cur,
                          int* __restrict__ csr, const int* __restrict__ flag) {
    int i = blockIdx.x * blockDim.x + threadIdx.x;
    if (i >= ETOT) return;
    int f = flag[0];
    int s, d;
    if (i < NEDGES) { s = ld_idx(ei, i, f); d = ld_idx(ei, (size_t)NEDGES + i, f); }
    else            { s = d = i - NEDGES; }
    int pos = atomicAdd(&cur[d], 1);
    csr[pos] = s;
}

// ---------------- conversions to bf16 staging ----------------
// input (fp32 or bf16 per flag) -> bf16 row-major
__global__ void k_cvt_in(const void* __restrict__ X, __hip_bfloat16* __restrict__ Xb,
                         const int* __restrict__ flag, int n) {
    int i = blockIdx.x * 256 + threadIdx.x;
    if (i >= n) return;
    Xb[i] = __float2bfloat16(ldf(X, i, flag[1]));
}
// fp32 -> bf16
__global__ void k_cvt_f32(const float* __restrict__ X, __hip_bfloat16* __restrict__ Xb, int n) {
    int i = blockIdx.x * 256 + threadIdx.x;
    if (i >= n) return;
    Xb[i] = __float2bfloat16(X[i]);
}
// W [256,256] (fp32 or bf16) -> transposed bf16 Wt[n,k]
__global__ void k_wt(const void* __restrict__ W, __hip_bfloat16* __restrict__ Wt,
                     const int* __restrict__ flag) {
    int i = blockIdx.x * 256 + threadIdx.x;  // 65536
    int k = i >> 8, n = i & 255;
    Wt[(size_t)n * 256 + k] = __float2bfloat16(ldf(W, (size_t)k * 256 + n, flag[1]));
}

// ---------------- GEMM: H[M,256] = A[M,256] @ Wt^T, bf16 in, FP32 out ----------------
// A frag: lane holds A[m=lane&15][k=(lane>>4)*8+j]; B mirrors with n=lane&15.
// D frag: col=lane&15, row=(lane>>4)*4+reg (m89/m91-verified).
__global__ __launch_bounds__(256) void k_gemm(const __hip_bfloat16* __restrict__ A,
                                              const __hip_bfloat16* __restrict__ Bt,
                                              float* __restrict__ Hout) {
    int m0   = blockIdx.x * 16;
    int w    = threadIdx.x >> 6;
    int lane = threadIdx.x & 63;
    int mr   = lane & 15;
    int quad = lane >> 4;
    f32x4 acc[4];
#pragma unroll
    for (int j = 0; j < 4; j++) acc[j] = (f32x4){0.f, 0.f, 0.f, 0.f};
    const __hip_bfloat16* arow = A + (size_t)(m0 + mr) * HC;
    for (int kk = 0; kk < HC; kk += 32) {
        bf16x8 a = *reinterpret_cast<const bf16x8*>(arow + kk + quad * 8);
#pragma unroll
        for (int j = 0; j < 4; j++) {
            int n = w * 64 + j * 16 + mr;
            bf16x8 b = *reinterpret_cast<const bf16x8*>(Bt + (size_t)n * HC + kk + quad * 8);
            acc[j] = __builtin_amdgcn_mfma_f32_16x16x32_bf16(a, b, acc[j], 0, 0, 0);
        }
    }
#pragma unroll
    for (int j = 0; j < 4; j++)
#pragma unroll
        for (int r = 0; r < 4; r++) {
            int row = m0 + quad * 4 + r;
            int col = w * 64 + j * 16 + mr;
            Hout[(size_t)row * HC + col] = acc[j][r];
        }
}

// ---------------- per-node attention scores es/ed (fp32 h) ----------------
__global__ __launch_bounds__(256) void k_scores(const float* __restrict__ Hf,
                                                const void* __restrict__ a_src,
                                                const void* __restrict__ a_dst,
                                                const int* __restrict__ flag,
                                                float* __restrict__ es, float* __restrict__ ed) {
    int nid  = blockIdx.x * 4 + (threadIdx.x >> 6);
    int lane = threadIdx.x & 63;
    int bf   = flag[1];
    const float* hrow = Hf + (size_t)nid * HC;
    float vs[4], vd[4];
#pragma unroll
    for (int hh = 0; hh < 4; hh++) {
        float hv = hrow[hh * 64 + lane];
        vs[hh] = hv * ldf(a_src, hh * 64 + lane, bf);
        vd[hh] = hv * ldf(a_dst, hh * 64 + lane, bf);
    }
#pragma unroll
    for (int hh = 0; hh < 4; hh++)
        for (int off = 32; off; off >>= 1) {
            vs[hh] += __shfl_xor(vs[hh], off);
            vd[hh] += __shfl_xor(vd[hh], off);
        }
    if (lane == 0)
        for (int hh = 0; hh < 4; hh++) { es[nid * 4 + hh] = vs[hh]; ed[nid * 4 + hh] = vd[hh]; }
}

// ---------------- per-dst softmax + aggregation (online, chunked) ----------------
__global__ __launch_bounds__(256) void k_agg(const float* __restrict__ Hf,
                                             const float* __restrict__ es, const float* __restrict__ ed,
                                             const void* __restrict__ bias,
                                             const int* __restrict__ off, const int* __restrict__ csr,
                                             const int* __restrict__ flag,
                                             float* __restrict__ Xout) {
    __shared__ float e_lds[EMAX * 4];
    __shared__ int   src_lds[EMAX];
    __shared__ float red[256];
    __shared__ float m_sh[4], d_sh[4], sc_sh[4], ed_sh[4];
    int n    = blockIdx.x;
    int t    = threadIdx.x;
    int head = t >> 6;
    int jg   = t >> 2;   // 0..63
    int h4   = t & 3;
    int base = off[n];
    int deg  = off[n + 1] - base;
    if (t < 4) { ed_sh[t] = ed[n * 4 + t]; m_sh[t] = -INFINITY; d_sh[t] = 0.f; }
    float acc = 0.f;
    for (int c0 = 0; c0 < deg; c0 += EMAX) {
        int cn = min(deg - c0, EMAX);
        __syncthreads();  // ed_sh ready / previous aggregation done
        for (int j = jg; j < cn; j += 64) {
            int s   = csr[base + c0 + j];
            float e = es[s * 4 + h4] + ed_sh[h4];
            e = (e > 0.f) ? e : 0.2f * e;
            e_lds[j * 4 + h4] = e;
            if (h4 == 0) src_lds[j] = s;
        }
        __syncthreads();
        float pm = -INFINITY;
        for (int j = jg; j < cn; j += 64) pm = fmaxf(pm, e_lds[j * 4 + h4]);
        red[t] = pm; __syncthreads();
        for (int s2 = 32; s2 >= 1; s2 >>= 1) {
            if (jg < s2) red[t] = fmaxf(red[t], red[(jg + s2) * 4 + h4]);
            __syncthreads();
        }
        if (t < 4) {
            float cm = red[t], om = m_sh[t];
            float nm = fmaxf(om, cm);
            sc_sh[t] = (om == -INFINITY) ? 0.f : __expf(om - nm);
            m_sh[t]  = nm;
        }
        __syncthreads();
        float nm = m_sh[h4], ps = 0.f;
        for (int j = jg; j < cn; j += 64) {
            float p = __expf(e_lds[j * 4 + h4] - nm);
            e_lds[j * 4 + h4] = p;
            ps += p;
        }
        red[t] = ps; __syncthreads();
        for (int s2 = 32; s2 >= 1; s2 >>= 1) {
            if (jg < s2) red[t] += red[(jg + s2) * 4 + h4];
            __syncthreads();
        }
        acc *= sc_sh[head];
        if (t < 4) d_sh[t] = d_sh[t] * sc_sh[t] + red[t];
        __syncthreads();
        for (int j = 0; j < cn; j++) {
            int s   = src_lds[j];
            float p = e_lds[j * 4 + head];
            acc = fmaf(p, Hf[(size_t)s * HC + t], acc);
        }
    }
    __syncthreads();
    float denom = fmaxf(d_sh[head], 1e-16f);
    float v = acc / denom + ldf(bias, t, flag[1]);
    v = fmaxf(v, 0.f);
    Xout[(size_t)n * HC + t] = v;
}

// ---------------- readout ----------------
__global__ __launch_bounds__(256) void k_groupsum(const float* __restrict__ X2,
                                                  const int* __restrict__ batch,
                                                  float* __restrict__ sx, int* __restrict__ cnt,
                                                  const int* __restrict__ flag) {
    int g = blockIdx.x;
    int t = threadIdx.x;
    int f = flag[0];
    int lo = 0, hi = NNODES;
    while (lo < hi) { int m = (lo + hi) >> 1; if (ld_idx(batch, m, f) < g) lo = m + 1; else hi = m; }
    int start = lo;
    hi = NNODES;
    while (lo < hi) { int m = (lo + hi) >> 1; if (ld_idx(batch, m, f) < g + 1) lo = m + 1; else hi = m; }
    int end = lo;
    float acc = 0.f;
    for (int nn = start; nn < end; nn++) acc += X2[(size_t)nn * HC + t];
    sx[g * HC + t] = acc;
    if (t == 0) cnt[g] = end - start;
}

__global__ __launch_bounds__(256) void k_final(const float* __restrict__ sx,
                                               const void* __restrict__ Wp,
                                               const void* __restrict__ bp,
                                               const int* __restrict__ cnt,
                                               const int* __restrict__ flag,
                                               void* __restrict__ out) {
    int i = blockIdx.x * 256 + threadIdx.x;  // 2048 = 64*32
    int g = i >> 5, c = i & 31;
    int bf = flag[1];
    float acc = 0.f;
    const float* sxg = sx + (size_t)g * HC;
    for (int k = 0; k < HC; k++) acc = fmaf(sxg[k], ldf(Wp, (size_t)k * DOUT + c, bf), acc);
    int ct = cnt[g];
    float v = (ct > 0) ? (acc / ct + ldf(bp, c, bf)) : 0.f;
    if (bf) ((__hip_bfloat16*)out)[i] = __float2bfloat16(v);
    else    ((float*)out)[i] = v;
}

extern "C" void kernel_launch(void* const* d_in, const int* in_sizes, int n_in,
                              void* d_out, int out_size, void* d_ws, size_t ws_size,
                              hipStream_t stream) {
    (void)in_sizes; (void)n_in; (void)out_size; (void)ws_size;
    const void* x   = d_in[0];
    const int*  ei  = (const int*)d_in[1];
    const int*  bat = (const int*)d_in[2];
    const void* W1  = d_in[3];
    const void* as1 = d_in[4];
    const void* ad1 = d_in[5];
    const void* b1  = d_in[6];
    const void* W2  = d_in[7];
    const void* as2 = d_in[8];
    const void* ad2 = d_in[9];
    const void* b2  = d_in[10];
    const void* Wp  = d_in[11];
    const void* bp  = d_in[12];

    char* ws = (char*)d_ws;
    size_t o = 0;
    auto alloc = [&](size_t bytes) -> char* {
        char* p = ws + o;
        o += (bytes + 255) & ~(size_t)255;
        return p;
    };
    float* hbuf = (float*)alloc((size_t)NNODES * HC * 4);           // fp32 h
    float* xbuf = (float*)alloc((size_t)NNODES * HC * 4);           // fp32 layer outputs
    __hip_bfloat16* xb = (__hip_bfloat16*)alloc((size_t)NNODES * HC * 2);  // bf16 GEMM A staging
    __hip_bfloat16* Wt = (__hip_bfloat16*)alloc((size_t)HC * HC * 2);
    float* es = (float*)alloc((size_t)NNODES * 4 * 4);
    float* ed = (float*)alloc((size_t)NNODES * 4 * 4);
    int* deg  = (int*)alloc((size_t)NNODES * 4);
    int* cur  = (int*)alloc((size_t)NNODES * 4);
    int* off  = (int*)alloc((size_t)(NNODES + 1) * 4);
    int* csr  = (int*)alloc((size_t)ETOT * 4);
    float* sx = (float*)alloc((size_t)NGROUP * HC * 4);
    int* cnt  = (int*)alloc((size_t)NGROUP * 4);
    int* flag = (int*)alloc(256);

    const int NXW = NNODES * HC;  // 5.12M elements

    // probes + CSR
    k_probe<<<1, 64, 0, stream>>>((const unsigned int*)x, ei, flag);
    hipMemsetAsync(deg, 0, (size_t)NNODES * 4, stream);
    k_hist<<<(ETOT + 255) / 256, 256, 0, stream>>>(ei, deg, flag);
    k_scan<<<1, 512, 0, stream>>>(deg, off, cur);
    k_scatter<<<(ETOT + 255) / 256, 256, 0, stream>>>(ei, cur, csr, flag);

    // Layer 1
    k_cvt_in<<<(NXW + 255) / 256, 256, 0, stream>>>(x, xb, flag, NXW);
    k_wt<<<256, 256, 0, stream>>>(W1, Wt, flag);
    k_gemm<<<NNODES / 16, 256, 0, stream>>>(xb, Wt, hbuf);
    k_scores<<<NNODES / 4, 256, 0, stream>>>(hbuf, as1, ad1, flag, es, ed);
    k_agg<<<NNODES, 256, 0, stream>>>(hbuf, es, ed, b1, off, csr, flag, xbuf);

    // Layer 2
    k_cvt_f32<<<(NXW + 255) / 256, 256, 0, stream>>>(xbuf, xb, NXW);
    k_wt<<<256, 256, 0, stream>>>(W2, Wt, flag);
    k_gemm<<<NNODES / 16, 256, 0, stream>>>(xb, Wt, hbuf);
    k_scores<<<NNODES / 4, 256, 0, stream>>>(hbuf, as2, ad2, flag, es, ed);
    k_agg<<<NNODES, 256, 0, stream>>>(hbuf, es, ed, b2, off, csr, flag, xbuf);

    // Readout
    k_groupsum<<<NGROUP, 256, 0, stream>>>(xbuf, bat, sx, cnt, flag);
    k_final<<<8, 256, 0, stream>>>(sx, Wp, bp, cnt, flag, d_out);
}

// Round 4
// 553.875 us; speedup vs baseline: 1.1585x; 1.1585x over previous
//
#include <hip/hip_runtime.h>
#include <hip/hip_bf16.h>
#include <cstdint>

#define NNODES 20000
#define NEDGES 640000
#define ETOT   (NEDGES + NNODES)
#define NGROUP 64
#define HC     256
#define DOUT   32
#define EMAX   256

typedef short bf16x8 __attribute__((ext_vector_type(8)));  // 8 bf16 in 4 VGPRs
typedef float f32x4  __attribute__((ext_vector_type(4)));

__device__ __forceinline__ float b2f(__hip_bfloat16 v) { return __bfloat162float(v); }

__device__ __forceinline__ short f2bs(float v) {
    __hip_bfloat16 b = __float2bfloat16(v);
    union { __hip_bfloat16 b; short s; } u; u.b = b; return u.s;
}

// float load robust to fp32 vs bf16 storage
__device__ __forceinline__ float ldf(const void* __restrict__ p, size_t i, int bf) {
    return bf ? __bfloat162float(((const __hip_bfloat16*)p)[i]) : ((const float*)p)[i];
}
// int load robust to int32 vs int64 storage (little-endian low word)
__device__ __forceinline__ int ld_idx(const int* __restrict__ p, size_t i, int f64) {
    return f64 ? p[2 * i] : p[i];
}

// ---------------- probe + deg zero ----------------
// flag[0]: edge_index int64?  flag[1]: floats bf16?
__global__ void k_probe(const unsigned int* __restrict__ xw, const int* __restrict__ ei,
                        int* __restrict__ flag, int* __restrict__ deg) {
    int t = blockIdx.x * 256 + threadIdx.x;
    for (int i = t; i < NNODES; i += 256 * 32) deg[i] = 0;
    if (t == 0) {
        int ones = 0;
        for (int i = 0; i < 256; i++) ones += (xw[i] >> 14) & 1;  // fp32 mantissa ~50%, bf16-pair exp MSB ~5%
        flag[1] = (ones < 64) ? 1 : 0;
        int zeros = 0;
        for (int i = 0; i < 256; i++) zeros += (ei[2 * i + 1] == 0) ? 1 : 0;
        flag[0] = (zeros > 200) ? 1 : 0;
    }
}

// ---------------- CSR build over dst ----------------
__global__ void k_hist(const int* __restrict__ ei, int* __restrict__ deg,
                       const int* __restrict__ flag) {
    int i = blockIdx.x * blockDim.x + threadIdx.x;
    if (i >= ETOT) return;
    int f = flag[0];
    int d = (i < NEDGES) ? ld_idx(ei, (size_t)NEDGES + i, f) : (i - NEDGES);
    atomicAdd(&deg[d], 1);
}

__global__ void k_scan(const int* __restrict__ deg, int* __restrict__ off, int* __restrict__ cur,
                       float* __restrict__ sx) {
    __shared__ int part[512];
    int t = threadIdx.x;
    for (int i = t; i < NGROUP * HC; i += 512) sx[i] = 0.f;   // zero group sums for later
    const int chunk = (NNODES + 511) / 512;  // 40
    int s = t * chunk, e = min(s + chunk, NNODES);
    int sum = 0;
    for (int i = s; i < e; i++) sum += deg[i];
    part[t] = sum;
    __syncthreads();
    if (t == 0) {
        int acc = 0;
        for (int i = 0; i < 512; i++) { int v = part[i]; part[i] = acc; acc += v; }
    }
    __syncthreads();
    int run = part[t];
    for (int i = s; i < e; i++) { off[i] = run; cur[i] = run; run += deg[i]; }
    if (t == 511) off[NNODES] = run;  // == ETOT
}

__global__ void k_scatter(const int* __restrict__ ei, int* __restrict__ cur,
                          int* __restrict__ csr, const int* __restrict__ flag) {
    int i = blockIdx.x * blockDim.x + threadIdx.x;
    if (i >= ETOT) return;
    int f = flag[0];
    int s, d;
    if (i < NEDGES) { s = ld_idx(ei, i, f); d = ld_idx(ei, (size_t)NEDGES + i, f); }
    else            { s = d = i - NEDGES; }
    int pos = atomicAdd(&cur[d], 1);
    csr[pos] = s;
}

// ---------------- both weight transposes, one launch ----------------
__global__ void k_wt(const void* __restrict__ W1, const void* __restrict__ W2,
                     __hip_bfloat16* __restrict__ Wt1, __hip_bfloat16* __restrict__ Wt2,
                     const int* __restrict__ flag) {
    int i = blockIdx.x * 256 + threadIdx.x;  // 131072
    int which = i >> 16;
    int j = i & 65535;
    int k = j >> 8, n = j & 255;
    const void* W = which ? W2 : W1;
    __hip_bfloat16* Wt = which ? Wt2 : Wt1;
    Wt[(size_t)n * 256 + k] = __float2bfloat16(ldf(W, (size_t)k * 256 + n, flag[1]));
}

// ---------------- GEMM: H[M,256] = A[M,256] @ Wt^T -> bf16 H ----------------
// A frag: lane holds A[m=lane&15][k=(lane>>4)*8+j]; B mirrors with n=lane&15.
// D frag: col=lane&15, row=(lane>>4)*4+reg (m89/m91-verified).
__global__ __launch_bounds__(256) void k_gemm(const void* __restrict__ A,
                                              const __hip_bfloat16* __restrict__ Bt,
                                              __hip_bfloat16* __restrict__ Hout,
                                              const int* __restrict__ flag, int force_bf) {
    int abf  = force_bf | flag[1];
    int m0   = blockIdx.x * 16;
    int w    = threadIdx.x >> 6;
    int lane = threadIdx.x & 63;
    int mr   = lane & 15;
    int quad = lane >> 4;
    f32x4 acc[4];
#pragma unroll
    for (int j = 0; j < 4; j++) acc[j] = (f32x4){0.f, 0.f, 0.f, 0.f};
    size_t rowoff = (size_t)(m0 + mr) * HC;
    for (int kk = 0; kk < HC; kk += 32) {
        bf16x8 a;
        if (abf) {
            a = *reinterpret_cast<const bf16x8*>((const __hip_bfloat16*)A + rowoff + kk + quad * 8);
        } else {
            const float* af = (const float*)A + rowoff + kk + quad * 8;
            f32x4 lo = *reinterpret_cast<const f32x4*>(af);
            f32x4 hi = *reinterpret_cast<const f32x4*>(af + 4);
#pragma unroll
            for (int ii = 0; ii < 4; ii++) { a[ii] = f2bs(lo[ii]); a[ii + 4] = f2bs(hi[ii]); }
        }
#pragma unroll
        for (int j = 0; j < 4; j++) {
            int n = w * 64 + j * 16 + mr;
            bf16x8 b = *reinterpret_cast<const bf16x8*>(Bt + (size_t)n * HC + kk + quad * 8);
            acc[j] = __builtin_amdgcn_mfma_f32_16x16x32_bf16(a, b, acc[j], 0, 0, 0);
        }
    }
#pragma unroll
    for (int j = 0; j < 4; j++)
#pragma unroll
        for (int r = 0; r < 4; r++) {
            int row = m0 + quad * 4 + r;
            int col = w * 64 + j * 16 + mr;
            Hout[(size_t)row * HC + col] = __float2bfloat16(acc[j][r]);
        }
}

// ---------------- per-node attention scores es/ed (bf16 h) ----------------
__global__ __launch_bounds__(256) void k_scores(const __hip_bfloat16* __restrict__ Hb,
                                                const void* __restrict__ a_src,
                                                const void* __restrict__ a_dst,
                                                const int* __restrict__ flag,
                                                float* __restrict__ es, float* __restrict__ ed) {
    int nid  = blockIdx.x * 4 + (threadIdx.x >> 6);
    int lane = threadIdx.x & 63;
    int bf   = flag[1];
    const __hip_bfloat16* hrow = Hb + (size_t)nid * HC;
    float vs[4], vd[4];
#pragma unroll
    for (int hh = 0; hh < 4; hh++) {
        float hv = b2f(hrow[hh * 64 + lane]);
        vs[hh] = hv * ldf(a_src, hh * 64 + lane, bf);
        vd[hh] = hv * ldf(a_dst, hh * 64 + lane, bf);
    }
#pragma unroll
    for (int hh = 0; hh < 4; hh++)
        for (int off = 32; off; off >>= 1) {
            vs[hh] += __shfl_xor(vs[hh], off);
            vd[hh] += __shfl_xor(vd[hh], off);
        }
    if (lane == 0)
        for (int hh = 0; hh < 4; hh++) { es[nid * 4 + hh] = vs[hh]; ed[nid * 4 + hh] = vd[hh]; }
}

// ---------------- per-dst softmax + aggregation (online, chunked, bf16 gather) ----------------
__global__ __launch_bounds__(256) void k_agg(const __hip_bfloat16* __restrict__ Hb,
                                             const float* __restrict__ es, const float* __restrict__ ed,
                                             const void* __restrict__ bias,
                                             const int* __restrict__ off, const int* __restrict__ csr,
                                             const int* __restrict__ flag,
                                             void* __restrict__ out, int out_bf) {
    __shared__ float e_lds[EMAX * 4];
    __shared__ int   src_lds[EMAX];
    __shared__ float red[256];
    __shared__ float m_sh[4], d_sh[4], sc_sh[4], ed_sh[4];
    int n    = blockIdx.x;
    int t    = threadIdx.x;
    int head = t >> 6;
    int jg   = t >> 2;   // 0..63
    int h4   = t & 3;
    int base = off[n];
    int deg  = off[n + 1] - base;
    if (t < 4) { ed_sh[t] = ed[n * 4 + t]; m_sh[t] = -INFINITY; d_sh[t] = 0.f; }
    float acc = 0.f;
    for (int c0 = 0; c0 < deg; c0 += EMAX) {
        int cn = min(deg - c0, EMAX);
        __syncthreads();  // ed_sh ready / previous chunk's aggregation done
        for (int j = jg; j < cn; j += 64) {
            int s   = csr[base + c0 + j];
            float e = es[s * 4 + h4] + ed_sh[h4];
            e = (e > 0.f) ? e : 0.2f * e;
            e_lds[j * 4 + h4] = e;
            if (h4 == 0) src_lds[j] = s;
        }
        __syncthreads();
        float pm = -INFINITY;
        for (int j = jg; j < cn; j += 64) pm = fmaxf(pm, e_lds[j * 4 + h4]);
        red[t] = pm; __syncthreads();
        for (int s2 = 32; s2 >= 1; s2 >>= 1) {
            if (jg < s2) red[t] = fmaxf(red[t], red[(jg + s2) * 4 + h4]);
            __syncthreads();
        }
        if (t < 4) {
            float cm = red[t], om = m_sh[t];
            float nm = fmaxf(om, cm);
            sc_sh[t] = (om == -INFINITY) ? 0.f : __expf(om - nm);
            m_sh[t]  = nm;
        }
        __syncthreads();
        float nm = m_sh[h4], ps = 0.f;
        for (int j = jg; j < cn; j += 64) {
            float p = __expf(e_lds[j * 4 + h4] - nm);
            e_lds[j * 4 + h4] = p;
            ps += p;
        }
        red[t] = ps; __syncthreads();
        for (int s2 = 32; s2 >= 1; s2 >>= 1) {
            if (jg < s2) red[t] += red[(jg + s2) * 4 + h4];
            __syncthreads();
        }
        acc *= sc_sh[head];
        if (t < 4) d_sh[t] = d_sh[t] * sc_sh[t] + red[t];
        __syncthreads();
        for (int j = 0; j < cn; j++) {
            int s   = src_lds[j];
            float p = e_lds[j * 4 + head];
            acc = fmaf(p, b2f(Hb[(size_t)s * HC + t]), acc);
        }
    }
    __syncthreads();
    float denom = fmaxf(d_sh[head], 1e-16f);
    float v = acc / denom + ldf(bias, t, flag[1]);
    v = fmaxf(v, 0.f);
    if (out_bf) ((__hip_bfloat16*)out)[(size_t)n * HC + t] = __float2bfloat16(v);
    else        ((float*)out)[(size_t)n * HC + t] = v;
}

// ---------------- readout: boundary-flush group sums (batch sorted), 80 blocks ----------------
__global__ __launch_bounds__(256) void k_groupsum(const float* __restrict__ X2,
                                                  const int* __restrict__ batch,
                                                  float* __restrict__ sx,
                                                  const int* __restrict__ flag) {
    const int RPB = NNODES / 80;  // 250
    int b = blockIdx.x, t = threadIdx.x, f = flag[0];
    int r0 = b * RPB, r1 = r0 + RPB;
    float acc = 0.f;
    int curg = ld_idx(batch, r0, f);
    for (int r = r0; r < r1; r++) {
        int g = ld_idx(batch, r, f);
        if (g != curg) { atomicAdd(&sx[(size_t)curg * HC + t], acc); acc = 0.f; curg = g; }
        acc += X2[(size_t)r * HC + t];
    }
    atomicAdd(&sx[(size_t)curg * HC + t], acc);
}

__global__ __launch_bounds__(256) void k_final(const float* __restrict__ sx,
                                               const void* __restrict__ Wp,
                                               const void* __restrict__ bp,
                                               const int* __restrict__ batch,
                                               const int* __restrict__ flag,
                                               void* __restrict__ out) {
    int i = blockIdx.x * 256 + threadIdx.x;  // 2048 = 64*32
    int g = i >> 5, c = i & 31;
    int bf = flag[1], f = flag[0];
    int lo = 0, hi = NNODES;
    while (lo < hi) { int m = (lo + hi) >> 1; if (ld_idx(batch, m, f) < g) lo = m + 1; else hi = m; }
    int start = lo;
    hi = NNODES;
    while (lo < hi) { int m = (lo + hi) >> 1; if (ld_idx(batch, m, f) < g + 1) lo = m + 1; else hi = m; }
    int ct = lo - start;
    float acc = 0.f;
    const float* sxg = sx + (size_t)g * HC;
    for (int k = 0; k < HC; k++) acc = fmaf(sxg[k], ldf(Wp, (size_t)k * DOUT + c, bf), acc);
    float v = (ct > 0) ? (acc / ct + ldf(bp, c, bf)) : 0.f;
    if (bf) ((__hip_bfloat16*)out)[i] = __float2bfloat16(v);
    else    ((float*)out)[i] = v;
}

extern "C" void kernel_launch(void* const* d_in, const int* in_sizes, int n_in,
                              void* d_out, int out_size, void* d_ws, size_t ws_size,
                              hipStream_t stream) {
    (void)in_sizes; (void)n_in; (void)out_size; (void)ws_size;
    const void* x   = d_in[0];
    const int*  ei  = (const int*)d_in[1];
    const int*  bat = (const int*)d_in[2];
    const void* W1  = d_in[3];
    const void* as1 = d_in[4];
    const void* ad1 = d_in[5];
    const void* b1  = d_in[6];
    const void* W2  = d_in[7];
    const void* as2 = d_in[8];
    const void* ad2 = d_in[9];
    const void* b2  = d_in[10];
    const void* Wp  = d_in[11];
    const void* bp  = d_in[12];

    char* ws = (char*)d_ws;
    size_t o = 0;
    auto alloc = [&](size_t bytes) -> char* {
        char* p = ws + o;
        o += (bytes + 255) & ~(size_t)255;
        return p;
    };
    __hip_bfloat16* hb  = (__hip_bfloat16*)alloc((size_t)NNODES * HC * 2);  // bf16 h
    __hip_bfloat16* xb  = (__hip_bfloat16*)alloc((size_t)NNODES * HC * 2);  // bf16 layer-1 out
    float* xf = (float*)alloc((size_t)NNODES * HC * 4);                     // fp32 layer-2 out
    __hip_bfloat16* Wt1 = (__hip_bfloat16*)alloc((size_t)HC * HC * 2);
    __hip_bfloat16* Wt2 = (__hip_bfloat16*)alloc((size_t)HC * HC * 2);
    float* es = (float*)alloc((size_t)NNODES * 4 * 4);
    float* ed = (float*)alloc((size_t)NNODES * 4 * 4);
    int* deg  = (int*)alloc((size_t)NNODES * 4);
    int* cur  = (int*)alloc((size_t)NNODES * 4);
    int* off  = (int*)alloc((size_t)(NNODES + 1) * 4);
    int* csr  = (int*)alloc((size_t)ETOT * 4);
    float* sx = (float*)alloc((size_t)NGROUP * HC * 4);
    int* flag = (int*)alloc(256);

    // probe + CSR (shared by both layers)
    k_probe<<<32, 256, 0, stream>>>((const unsigned int*)x, ei, flag, deg);
    k_hist<<<(ETOT + 255) / 256, 256, 0, stream>>>(ei, deg, flag);
    k_scan<<<1, 512, 0, stream>>>(deg, off, cur, sx);
    k_scatter<<<(ETOT + 255) / 256, 256, 0, stream>>>(ei, cur, csr, flag);
    k_wt<<<512, 256, 0, stream>>>(W1, W2, Wt1, Wt2, flag);

    // Layer 1
    k_gemm<<<NNODES / 16, 256, 0, stream>>>(x, Wt1, hb, flag, 0);
    k_scores<<<NNODES / 4, 256, 0, stream>>>(hb, as1, ad1, flag, es, ed);
    k_agg<<<NNODES, 256, 0, stream>>>(hb, es, ed, b1, off, csr, flag, xb, 1);

    // Layer 2
    k_gemm<<<NNODES / 16, 256, 0, stream>>>(xb, Wt2, hb, flag, 1);
    k_scores<<<NNODES / 4, 256, 0, stream>>>(hb, as2, ad2, flag, es, ed);
    k_agg<<<NNODES, 256, 0, stream>>>(hb, es, ed, b2, off, csr, flag, xf, 0);

    // Readout
    k_groupsum<<<80, 256, 0, stream>>>(xf, bat, sx, flag);
    k_final<<<8, 256, 0, stream>>>(sx, Wp, bp, bat, flag, d_out);
}

// Round 5
// 402.761 us; speedup vs baseline: 1.5932x; 1.3752x over previous
//
#include <hip/hip_runtime.h>
#include <hip/hip_bf16.h>
#include <cstdint>

#define NNODES 20000
#define NEDGES 640000
#define ETOT   (NEDGES + NNODES)
#define NGROUP 64
#define HC     256
#define DOUT   32

typedef short bf16x8 __attribute__((ext_vector_type(8)));  // 8 bf16 in 4 VGPRs
typedef short s16x4  __attribute__((ext_vector_type(4)));
typedef float f32x4  __attribute__((ext_vector_type(4)));

__device__ __forceinline__ float b2f(__hip_bfloat16 v) { return __bfloat162float(v); }
__device__ __forceinline__ float bs2f(short v) {
    union { unsigned int u; float f; } c; c.u = ((unsigned int)(unsigned short)v) << 16; return c.f;
}
__device__ __forceinline__ short f2bs(float v) {
    __hip_bfloat16 b = __float2bfloat16(v);
    union { __hip_bfloat16 b; short s; } u; u.b = b; return u.s;
}
// float load robust to fp32 vs bf16 storage
__device__ __forceinline__ float ldf(const void* __restrict__ p, size_t i, int bf) {
    return bf ? __bfloat162float(((const __hip_bfloat16*)p)[i]) : ((const float*)p)[i];
}
// int load robust to int32 vs int64 storage (little-endian low word)
__device__ __forceinline__ int ld_idx(const int* __restrict__ p, size_t i, int f64) {
    return f64 ? p[2 * i] : p[i];
}

// ---------------- probe (ballot-parallel) + deg zero ----------------
// flag[0]: edge_index int64?  flag[1]: floats bf16?
__global__ void k_probe(const unsigned int* __restrict__ xw, const int* __restrict__ ei,
                        int* __restrict__ flag, int* __restrict__ deg) {
    int t = blockIdx.x * 256 + threadIdx.x;
    for (int i = t; i < NNODES; i += 256 * 32) deg[i] = 0;
    if (blockIdx.x == 0 && threadIdx.x < 64) {
        int l = threadIdx.x;
        int ones = 0, zeros = 0;
#pragma unroll
        for (int r = 0; r < 4; r++) {
            unsigned long long b1 = __ballot((xw[r * 64 + l] >> 14) & 1);
            unsigned long long b2 = __ballot(ei[2 * (r * 64 + l) + 1] == 0);
            ones  += __popcll(b1);
            zeros += __popcll(b2);
        }
        if (l == 0) { flag[1] = (ones < 64) ? 1 : 0; flag[0] = (zeros > 200) ? 1 : 0; }
    }
}

// ---------------- CSR build over dst ----------------
__global__ void k_hist(const int* __restrict__ ei, int* __restrict__ deg,
                       const int* __restrict__ flag) {
    int i = blockIdx.x * blockDim.x + threadIdx.x;
    if (i >= ETOT) return;
    int f = flag[0];
    int d = (i < NEDGES) ? ld_idx(ei, (size_t)NEDGES + i, f) : (i - NEDGES);
    atomicAdd(&deg[d], 1);
}

__global__ void k_scan(const int* __restrict__ deg, int* __restrict__ off, int* __restrict__ cur,
                       float* __restrict__ sx) {
    __shared__ unsigned short dl[NNODES];  // 40 KB, coalesced-staged
    __shared__ int part[512];
    int t = threadIdx.x;
    for (int i = t; i < NGROUP * HC; i += 512) sx[i] = 0.f;  // zero group sums
    for (int i = t; i < NNODES; i += 512) dl[i] = (unsigned short)deg[i];
    __syncthreads();
    const int chunk = (NNODES + 511) / 512;  // 40
    int s = t * chunk, e = min(s + chunk, NNODES);
    int sum = 0;
    for (int i = s; i < e; i++) sum += dl[i];
    part[t] = sum;
    __syncthreads();
    if (t == 0) {
        int acc = 0;
        for (int i = 0; i < 512; i++) { int v = part[i]; part[i] = acc; acc += v; }
    }
    __syncthreads();
    int run = part[t];
    for (int i = s; i < e; i++) { off[i] = run; cur[i] = run; run += dl[i]; }
    if (t == 511) off[NNODES] = ETOT;
}

__global__ void k_scatter(const int* __restrict__ ei, int* __restrict__ cur,
                          int* __restrict__ csr, const int* __restrict__ flag) {
    int i = blockIdx.x * blockDim.x + threadIdx.x;
    if (i >= ETOT) return;
    int f = flag[0];
    int s, d;
    if (i < NEDGES) { s = ld_idx(ei, i, f); d = ld_idx(ei, (size_t)NEDGES + i, f); }
    else            { s = d = i - NEDGES; }
    int pos = atomicAdd(&cur[d], 1);
    csr[pos] = s;
}

// ---------------- both weight transposes, one launch ----------------
__global__ void k_wt(const void* __restrict__ W1, const void* __restrict__ W2,
                     __hip_bfloat16* __restrict__ Wt1, __hip_bfloat16* __restrict__ Wt2,
                     const int* __restrict__ flag) {
    int i = blockIdx.x * 256 + threadIdx.x;  // 131072
    int which = i >> 16;
    int j = i & 65535;
    int k = j >> 8, n = j & 255;
    const void* W = which ? W2 : W1;
    __hip_bfloat16* Wt = which ? Wt2 : Wt1;
    Wt[(size_t)n * 256 + k] = __float2bfloat16(ldf(W, (size_t)k * 256 + n, flag[1]));
}

// ---------------- GEMM + fused attention scores ----------------
// H[M,256] = A[M,256] @ Wt^T -> bf16 H; es/ed computed from fp32 accumulators.
// A frag: lane holds A[m=lane&15][k=(lane>>4)*8+j]; B mirrors with n=lane&15.
// D frag: col=lane&15, row=(lane>>4)*4+reg (m89/m91-verified).
// Wave w covers cols w*64..w*64+63 == exactly head w -> per-head dot needs only
// a 4-level shuffle reduce over the 16 mr-lanes.
__global__ __launch_bounds__(256) void k_gemm(const void* __restrict__ A,
                                              const __hip_bfloat16* __restrict__ Bt,
                                              __hip_bfloat16* __restrict__ Hout,
                                              const void* __restrict__ a_src,
                                              const void* __restrict__ a_dst,
                                              float* __restrict__ es, float* __restrict__ ed,
                                              const int* __restrict__ flag, int force_bf) {
    int bf   = flag[1];
    int abf  = force_bf | bf;
    int m0   = blockIdx.x * 16;
    int w    = threadIdx.x >> 6;
    int lane = threadIdx.x & 63;
    int mr   = lane & 15;
    int quad = lane >> 4;
    f32x4 acc[4];
#pragma unroll
    for (int j = 0; j < 4; j++) acc[j] = (f32x4){0.f, 0.f, 0.f, 0.f};
    size_t rowoff = (size_t)(m0 + mr) * HC;
    for (int kk = 0; kk < HC; kk += 32) {
        bf16x8 a;
        if (abf) {
            a = *reinterpret_cast<const bf16x8*>((const __hip_bfloat16*)A + rowoff + kk + quad * 8);
        } else {
            const float* af = (const float*)A + rowoff + kk + quad * 8;
            f32x4 lo = *reinterpret_cast<const f32x4*>(af);
            f32x4 hi = *reinterpret_cast<const f32x4*>(af + 4);
#pragma unroll
            for (int ii = 0; ii < 4; ii++) { a[ii] = f2bs(lo[ii]); a[ii + 4] = f2bs(hi[ii]); }
        }
#pragma unroll
        for (int j = 0; j < 4; j++) {
            int n = w * 64 + j * 16 + mr;
            bf16x8 b = *reinterpret_cast<const bf16x8*>(Bt + (size_t)n * HC + kk + quad * 8);
            acc[j] = __builtin_amdgcn_mfma_f32_16x16x32_bf16(a, b, acc[j], 0, 0, 0);
        }
    }
    // store H (bf16)
#pragma unroll
    for (int j = 0; j < 4; j++)
#pragma unroll
        for (int r = 0; r < 4; r++) {
            int row = m0 + quad * 4 + r;
            int col = w * 64 + j * 16 + mr;
            Hout[(size_t)row * HC + col] = __float2bfloat16(acc[j][r]);
        }
    // fused scores: es[row][w], ed[row][w]
    float ps[4] = {0.f, 0.f, 0.f, 0.f}, pd[4] = {0.f, 0.f, 0.f, 0.f};
#pragma unroll
    for (int j = 0; j < 4; j++) {
        float asv = ldf(a_src, (size_t)w * 64 + j * 16 + mr, bf);
        float adv = ldf(a_dst, (size_t)w * 64 + j * 16 + mr, bf);
#pragma unroll
        for (int r = 0; r < 4; r++) { ps[r] = fmaf(acc[j][r], asv, ps[r]); pd[r] = fmaf(acc[j][r], adv, pd[r]); }
    }
#pragma unroll
    for (int o = 1; o < 16; o <<= 1)
#pragma unroll
        for (int r = 0; r < 4; r++) { ps[r] += __shfl_xor(ps[r], o); pd[r] += __shfl_xor(pd[r], o); }
    if (mr == 0)
#pragma unroll
        for (int r = 0; r < 4; r++) {
            int row = m0 + quad * 4 + r;
            es[(size_t)row * 4 + w] = ps[r];
            ed[(size_t)row * 4 + w] = pd[r];
        }
}

// ---------------- wave-per-node softmax + aggregation (no __syncthreads) ----------------
// lane l owns features l*4..l*4+3 (all in head l>>4); edges processed in chunks of 64.
__global__ __launch_bounds__(256) void k_agg(const __hip_bfloat16* __restrict__ Hb,
                                             const float* __restrict__ es4, const float* __restrict__ ed4,
                                             const void* __restrict__ bias,
                                             const int* __restrict__ off, const int* __restrict__ csr,
                                             const int* __restrict__ flag,
                                             __hip_bfloat16* __restrict__ out) {
    __shared__ float p_lds[4][256];   // per-wave: 64 edges x 4 heads
    int wv = threadIdx.x >> 6;
    int l  = threadIdx.x & 63;
    int n  = blockIdx.x * 4 + wv;
    int hd = l >> 4;
    int base = off[n], deg = off[n + 1] - base;
    f32x4 edv = *reinterpret_cast<const f32x4*>(ed4 + (size_t)n * 4);
    f32x4 m    = (f32x4){-INFINITY, -INFINITY, -INFINITY, -INFINITY};
    f32x4 dsum = (f32x4){0.f, 0.f, 0.f, 0.f};
    f32x4 acc  = (f32x4){0.f, 0.f, 0.f, 0.f};
    for (int c0 = 0; c0 < deg; c0 += 64) {
        int cn = min(deg - c0, 64);
        int s = 0;
        f32x4 ev;
        if (l < cn) {
            s = csr[base + c0 + l];
            f32x4 e = *reinterpret_cast<const f32x4*>(es4 + (size_t)s * 4);
#pragma unroll
            for (int h = 0; h < 4; h++) {
                float t = e[h] + edv[h];
                ev[h] = (t > 0.f) ? t : 0.2f * t;
            }
        } else {
#pragma unroll
            for (int h = 0; h < 4; h++) ev[h] = -INFINITY;
        }
        // wave max per head
        f32x4 mc = ev;
#pragma unroll
        for (int o = 32; o; o >>= 1)
#pragma unroll
            for (int h = 0; h < 4; h++) mc[h] = fmaxf(mc[h], __shfl_xor(mc[h], o));
        // online-softmax update
        f32x4 al, pv;
#pragma unroll
        for (int h = 0; h < 4; h++) {
            float nm = fmaxf(m[h], mc[h]);
            al[h] = __expf(m[h] - nm);   // m=-inf on first chunk -> 0
            m[h]  = nm;
        }
#pragma unroll
        for (int h = 0; h < 4; h++) pv[h] = (l < cn) ? __expf(ev[h] - m[h]) : 0.f;
        f32x4 sc = pv;
#pragma unroll
        for (int o = 32; o; o >>= 1)
#pragma unroll
            for (int h = 0; h < 4; h++) sc[h] += __shfl_xor(sc[h], o);
#pragma unroll
        for (int h = 0; h < 4; h++) dsum[h] = dsum[h] * al[h] + sc[h];
        float ah = al[hd];
        acc *= ah;
        // broadcast p through LDS (wave-private region, no barrier needed)
        *reinterpret_cast<f32x4*>(&p_lds[wv][l * 4]) = pv;
        for (int j = 0; j < cn; j++) {
            int sj  = __shfl(s, j);
            float p = p_lds[wv][j * 4 + hd];
            s16x4 hv = *reinterpret_cast<const s16x4*>(Hb + (size_t)sj * HC + l * 4);
#pragma unroll
            for (int k = 0; k < 4; k++) acc[k] = fmaf(p, bs2f(hv[k]), acc[k]);
        }
    }
    float dd = fmaxf(dsum[hd], 1e-16f);
    int bf = flag[1];
    s16x4 ov;
#pragma unroll
    for (int k = 0; k < 4; k++) {
        float v = acc[k] / dd + ldf(bias, (size_t)l * 4 + k, bf);
        ov[k] = f2bs(fmaxf(v, 0.f));
    }
    *reinterpret_cast<s16x4*>(out + (size_t)n * HC + l * 4) = ov;
}

// ---------------- readout: boundary-flush group sums (batch sorted), 250 blocks ----------------
__global__ __launch_bounds__(256) void k_groupsum(const __hip_bfloat16* __restrict__ X2,
                                                  const int* __restrict__ batch,
                                                  float* __restrict__ sx,
                                                  const int* __restrict__ flag) {
    const int RPB = NNODES / 250;  // 80
    int b = blockIdx.x, t = threadIdx.x, f = flag[0];
    int r0 = b * RPB, r1 = r0 + RPB;
    float acc = 0.f;
    int curg = ld_idx(batch, r0, f);
    for (int r = r0; r < r1; r++) {
        int g = ld_idx(batch, r, f);
        if (g != curg) { atomicAdd(&sx[(size_t)curg * HC + t], acc); acc = 0.f; curg = g; }
        acc += b2f(X2[(size_t)r * HC + t]);
    }
    atomicAdd(&sx[(size_t)curg * HC + t], acc);
}

__global__ __launch_bounds__(256) void k_final(const float* __restrict__ sx,
                                               const void* __restrict__ Wp,
                                               const void* __restrict__ bp,
                                               const int* __restrict__ batch,
                                               const int* __restrict__ flag,
                                               void* __restrict__ out) {
    int i = blockIdx.x * 256 + threadIdx.x;  // 2048 = 64*32
    int g = i >> 5, c = i & 31;
    int bf = flag[1], f = flag[0];
    int lo = 0, hi = NNODES;
    while (lo < hi) { int m = (lo + hi) >> 1; if (ld_idx(batch, m, f) < g) lo = m + 1; else hi = m; }
    int start = lo;
    hi = NNODES;
    while (lo < hi) { int m = (lo + hi) >> 1; if (ld_idx(batch, m, f) < g + 1) lo = m + 1; else hi = m; }
    int ct = lo - start;
    float acc = 0.f;
    const float* sxg = sx + (size_t)g * HC;
    for (int k = 0; k < HC; k++) acc = fmaf(sxg[k], ldf(Wp, (size_t)k * DOUT + c, bf), acc);
    float v = (ct > 0) ? (acc / ct + ldf(bp, c, bf)) : 0.f;
    if (bf) ((__hip_bfloat16*)out)[i] = __float2bfloat16(v);
    else    ((float*)out)[i] = v;
}

extern "C" void kernel_launch(void* const* d_in, const int* in_sizes, int n_in,
                              void* d_out, int out_size, void* d_ws, size_t ws_size,
                              hipStream_t stream) {
    (void)in_sizes; (void)n_in; (void)out_size; (void)ws_size;
    const void* x   = d_in[0];
    const int*  ei  = (const int*)d_in[1];
    const int*  bat = (const int*)d_in[2];
    const void* W1  = d_in[3];
    const void* as1 = d_in[4];
    const void* ad1 = d_in[5];
    const void* b1  = d_in[6];
    const void* W2  = d_in[7];
    const void* as2 = d_in[8];
    const void* ad2 = d_in[9];
    const void* b2  = d_in[10];
    const void* Wp  = d_in[11];
    const void* bp  = d_in[12];

    char* ws = (char*)d_ws;
    size_t o = 0;
    auto alloc = [&](size_t bytes) -> char* {
        char* p = ws + o;
        o += (bytes + 255) & ~(size_t)255;
        return p;
    };
    __hip_bfloat16* hb  = (__hip_bfloat16*)alloc((size_t)NNODES * HC * 2);  // bf16 h
    __hip_bfloat16* xb  = (__hip_bfloat16*)alloc((size_t)NNODES * HC * 2);  // bf16 layer-1 out
    __hip_bfloat16* xb2 = (__hip_bfloat16*)alloc((size_t)NNODES * HC * 2);  // bf16 layer-2 out
    __hip_bfloat16* Wt1 = (__hip_bfloat16*)alloc((size_t)HC * HC * 2);
    __hip_bfloat16* Wt2 = (__hip_bfloat16*)alloc((size_t)HC * HC * 2);
    float* es = (float*)alloc((size_t)NNODES * 4 * 4);
    float* ed = (float*)alloc((size_t)NNODES * 4 * 4);
    int* deg  = (int*)alloc((size_t)NNODES * 4);
    int* cur  = (int*)alloc((size_t)NNODES * 4);
    int* off  = (int*)alloc((size_t)(NNODES + 1) * 4);
    int* csr  = (int*)alloc((size_t)ETOT * 4);
    float* sx = (float*)alloc((size_t)NGROUP * HC * 4);
    int* flag = (int*)alloc(256);

    // probe + CSR (shared by both layers)
    k_probe<<<32, 256, 0, stream>>>((const unsigned int*)x, ei, flag, deg);
    k_hist<<<(ETOT + 255) / 256, 256, 0, stream>>>(ei, deg, flag);
    k_scan<<<1, 512, 0, stream>>>(deg, off, cur, sx);
    k_scatter<<<(ETOT + 255) / 256, 256, 0, stream>>>(ei, cur, csr, flag);
    k_wt<<<512, 256, 0, stream>>>(W1, W2, Wt1, Wt2, flag);

    // Layer 1
    k_gemm<<<NNODES / 16, 256, 0, stream>>>(x, Wt1, hb, as1, ad1, es, ed, flag, 0);
    k_agg<<<NNODES / 4, 256, 0, stream>>>(hb, es, ed, b1, off, csr, flag, xb);

    // Layer 2
    k_gemm<<<NNODES / 16, 256, 0, stream>>>(xb, Wt2, hb, as2, ad2, es, ed, flag, 1);
    k_agg<<<NNODES / 4, 256, 0, stream>>>(hb, es, ed, b2, off, csr, flag, xb2);

    // Readout
    k_groupsum<<<250, 256, 0, stream>>>(xb2, bat, sx, flag);
    k_final<<<8, 256, 0, stream>>>(sx, Wp, bp, bat, flag, d_out);
}

// Round 6
// 395.825 us; speedup vs baseline: 1.6211x; 1.0175x over previous
//
#include <hip/hip_runtime.h>
#include <hip/hip_bf16.h>
#include <cstdint>

#define NNODES 20000
#define NEDGES 640000
#define ETOT   (NEDGES + NNODES)
#define NGROUP 64
#define HC     256
#define DOUT   32

typedef short bf16x8 __attribute__((ext_vector_type(8)));  // 8 bf16 in 4 VGPRs
typedef short s16x4  __attribute__((ext_vector_type(4)));
typedef float f32x4  __attribute__((ext_vector_type(4)));

__device__ __forceinline__ float b2f(__hip_bfloat16 v) { return __bfloat162float(v); }
__device__ __forceinline__ float bs2f(short v) {
    union { unsigned int u; float f; } c; c.u = ((unsigned int)(unsigned short)v) << 16; return c.f;
}
__device__ __forceinline__ short f2bs(float v) {
    __hip_bfloat16 b = __float2bfloat16(v);
    union { __hip_bfloat16 b; short s; } u; u.b = b; return u.s;
}
// float load robust to fp32 vs bf16 storage
__device__ __forceinline__ float ldf(const void* __restrict__ p, size_t i, int bf) {
    return bf ? __bfloat162float(((const __hip_bfloat16*)p)[i]) : ((const float*)p)[i];
}
// int load robust to int32 vs int64 storage (little-endian low word)
__device__ __forceinline__ int ld_idx(const int* __restrict__ p, size_t i, int f64) {
    return f64 ? p[2 * i] : p[i];
}

// ---------------- probe (ballot-parallel) + deg zero ----------------
// flag[0]: edge_index int64?  flag[1]: floats bf16?
__global__ void k_probe(const unsigned int* __restrict__ xw, const int* __restrict__ ei,
                        int* __restrict__ flag, int* __restrict__ deg) {
    int t = blockIdx.x * 256 + threadIdx.x;
    for (int i = t; i < NNODES; i += 256 * 32) deg[i] = 0;
    if (blockIdx.x == 0 && threadIdx.x < 64) {
        int l = threadIdx.x;
        int ones = 0, zeros = 0;
#pragma unroll
        for (int r = 0; r < 4; r++) {
            unsigned long long b1 = __ballot((xw[r * 64 + l] >> 14) & 1);
            unsigned long long b2 = __ballot(ei[2 * (r * 64 + l) + 1] == 0);
            ones  += __popcll(b1);
            zeros += __popcll(b2);
        }
        if (l == 0) { flag[1] = (ones < 64) ? 1 : 0; flag[0] = (zeros > 200) ? 1 : 0; }
    }
}

// ---------------- CSR build over dst ----------------
__global__ void k_hist(const int* __restrict__ ei, int* __restrict__ deg,
                       const int* __restrict__ flag) {
    int i = blockIdx.x * blockDim.x + threadIdx.x;
    if (i >= ETOT) return;
    int f = flag[0];
    int d = (i < NEDGES) ? ld_idx(ei, (size_t)NEDGES + i, f) : (i - NEDGES);
    atomicAdd(&deg[d], 1);
}

__global__ void k_scan(const int* __restrict__ deg, int* __restrict__ off, int* __restrict__ cur,
                       float* __restrict__ sx) {
    __shared__ unsigned short dl[NNODES];  // 40 KB, coalesced-staged
    __shared__ int wtot[8];
    int t = threadIdx.x;
    for (int i = t; i < NGROUP * HC; i += 512) sx[i] = 0.f;  // zero group sums
    for (int i = t; i < NNODES; i += 512) dl[i] = (unsigned short)deg[i];
    __syncthreads();
    const int chunk = (NNODES + 511) / 512;  // 40
    int s = t * chunk, e = min(s + chunk, NNODES);
    int sum = 0;
    for (int i = s; i < e; i++) sum += dl[i];
    // 512-thread inclusive scan: wave shuffle scan + cross-wave offsets
    int lane = t & 63, wv = t >> 6;
    int v = sum;
#pragma unroll
    for (int o = 1; o < 64; o <<= 1) {
        int u = __shfl_up(v, o);
        if (lane >= o) v += u;
    }
    if (lane == 63) wtot[wv] = v;
    __syncthreads();
    int woff = 0;
    for (int i = 0; i < wv; i++) woff += wtot[i];
    int run = woff + v - sum;  // exclusive prefix for this thread's chunk
    for (int i = s; i < e; i++) { off[i] = run; cur[i] = run; run += dl[i]; }
    if (t == 511) off[NNODES] = ETOT;
}

__global__ void k_scatter(const int* __restrict__ ei, int* __restrict__ cur,
                          int* __restrict__ csr, const int* __restrict__ flag) {
    int i = blockIdx.x * blockDim.x + threadIdx.x;
    if (i >= ETOT) return;
    int f = flag[0];
    int s, d;
    if (i < NEDGES) { s = ld_idx(ei, i, f); d = ld_idx(ei, (size_t)NEDGES + i, f); }
    else            { s = d = i - NEDGES; }
    int pos = atomicAdd(&cur[d], 1);
    csr[pos] = s;
}

// ---------------- both weight transposes, one launch ----------------
__global__ void k_wt(const void* __restrict__ W1, const void* __restrict__ W2,
                     __hip_bfloat16* __restrict__ Wt1, __hip_bfloat16* __restrict__ Wt2,
                     const int* __restrict__ flag) {
    int i = blockIdx.x * 256 + threadIdx.x;  // 131072
    int which = i >> 16;
    int j = i & 65535;
    int k = j >> 8, n = j & 255;
    const void* W = which ? W2 : W1;
    __hip_bfloat16* Wt = which ? Wt2 : Wt1;
    Wt[(size_t)n * 256 + k] = __float2bfloat16(ldf(W, (size_t)k * 256 + n, flag[1]));
}

// ---------------- GEMM (64-row blocks) + fused attention scores ----------------
// Block = 64 rows; wave w owns rows r0..r0+15 and ALL 256 cols (16 col-tiles).
// Bt read once per block (128 KB) -> L1/L2-hot across the 4 waves.
// A frag: lane holds A[m=lane&15][k=(lane>>4)*8+j]; B mirrors with n=lane&15.
// D frag: col=lane&15, row=(lane>>4)*4+reg (m89/m91-verified).
__global__ __launch_bounds__(256) void k_gemm(const void* __restrict__ A,
                                              const __hip_bfloat16* __restrict__ Bt,
                                              __hip_bfloat16* __restrict__ Hout,
                                              const void* __restrict__ a_src,
                                              const void* __restrict__ a_dst,
                                              float* __restrict__ es4, float* __restrict__ ed4,
                                              const int* __restrict__ flag, int force_bf) {
    int bf   = flag[1];
    int abf  = force_bf | bf;
    int w    = threadIdx.x >> 6;
    int lane = threadIdx.x & 63;
    int mr   = lane & 15;
    int quad = lane >> 4;
    int r0   = blockIdx.x * 64 + w * 16;
    if (r0 >= NNODES) return;
    f32x4 acc[16];
#pragma unroll
    for (int j = 0; j < 16; j++) acc[j] = (f32x4){0.f, 0.f, 0.f, 0.f};
    size_t rowoff = (size_t)(r0 + mr) * HC;
    for (int kk = 0; kk < HC; kk += 32) {
        bf16x8 a;
        if (abf) {
            a = *reinterpret_cast<const bf16x8*>((const __hip_bfloat16*)A + rowoff + kk + quad * 8);
        } else {
            const float* af = (const float*)A + rowoff + kk + quad * 8;
            f32x4 lo = *reinterpret_cast<const f32x4*>(af);
            f32x4 hi = *reinterpret_cast<const f32x4*>(af + 4);
#pragma unroll
            for (int ii = 0; ii < 4; ii++) { a[ii] = f2bs(lo[ii]); a[ii + 4] = f2bs(hi[ii]); }
        }
#pragma unroll
        for (int j = 0; j < 16; j++) {
            bf16x8 b = *reinterpret_cast<const bf16x8*>(Bt + (size_t)(j * 16 + mr) * HC + kk + quad * 8);
            acc[j] = __builtin_amdgcn_mfma_f32_16x16x32_bf16(a, b, acc[j], 0, 0, 0);
        }
    }
    // store H (bf16)
#pragma unroll
    for (int j = 0; j < 16; j++)
#pragma unroll
        for (int r = 0; r < 4; r++)
            Hout[(size_t)(r0 + quad * 4 + r) * HC + j * 16 + mr] = __float2bfloat16(acc[j][r]);
    // fused scores: es[row][h] = sum_cols h_row*a_src (h = j>>2)
    float ps[4][4], pd[4][4];
#pragma unroll
    for (int h = 0; h < 4; h++)
#pragma unroll
        for (int r = 0; r < 4; r++) { ps[h][r] = 0.f; pd[h][r] = 0.f; }
#pragma unroll
    for (int j = 0; j < 16; j++) {
        int h = j >> 2;
        float asv = ldf(a_src, (size_t)j * 16 + mr, bf);
        float adv = ldf(a_dst, (size_t)j * 16 + mr, bf);
#pragma unroll
        for (int r = 0; r < 4; r++) {
            ps[h][r] = fmaf(acc[j][r], asv, ps[h][r]);
            pd[h][r] = fmaf(acc[j][r], adv, pd[h][r]);
        }
    }
#pragma unroll
    for (int o = 1; o < 16; o <<= 1)
#pragma unroll
        for (int h = 0; h < 4; h++)
#pragma unroll
            for (int r = 0; r < 4; r++) {
                ps[h][r] += __shfl_xor(ps[h][r], o);
                pd[h][r] += __shfl_xor(pd[h][r], o);
            }
    if (mr == 0)
#pragma unroll
        for (int r = 0; r < 4; r++) {
            int row = r0 + quad * 4 + r;
            *reinterpret_cast<f32x4*>(es4 + (size_t)row * 4) =
                (f32x4){ps[0][r], ps[1][r], ps[2][r], ps[3][r]};
            *reinterpret_cast<f32x4*>(ed4 + (size_t)row * 4) =
                (f32x4){pd[0][r], pd[1][r], pd[2][r], pd[3][r]};
        }
}

// ---------------- wave-per-node softmax + aggregation (no __syncthreads) ----------------
// lane l owns features l*4..l*4+3 (all in head l>>4); edges in chunks of 64;
// gather loop 8-way unrolled for memory-level parallelism.
__global__ __launch_bounds__(256) void k_agg(const __hip_bfloat16* __restrict__ Hb,
                                             const float* __restrict__ es4, const float* __restrict__ ed4,
                                             const void* __restrict__ bias,
                                             const int* __restrict__ off, const int* __restrict__ csr,
                                             const int* __restrict__ flag,
                                             __hip_bfloat16* __restrict__ out) {
    __shared__ float p_lds[4][256];   // per-wave: 64 edges x 4 heads
    __shared__ int   s_lds[4][64];
    int wv = threadIdx.x >> 6;
    int l  = threadIdx.x & 63;
    int n  = blockIdx.x * 4 + wv;
    int hd = l >> 4;
    int base = off[n], deg = off[n + 1] - base;
    f32x4 edv = *reinterpret_cast<const f32x4*>(ed4 + (size_t)n * 4);
    f32x4 m    = (f32x4){-INFINITY, -INFINITY, -INFINITY, -INFINITY};
    f32x4 dsum = (f32x4){0.f, 0.f, 0.f, 0.f};
    f32x4 acc  = (f32x4){0.f, 0.f, 0.f, 0.f};
    for (int c0 = 0; c0 < deg; c0 += 64) {
        int cn = min(deg - c0, 64);
        f32x4 ev;
        if (l < cn) {
            int s = csr[base + c0 + l];
            s_lds[wv][l] = s;
            f32x4 e = *reinterpret_cast<const f32x4*>(es4 + (size_t)s * 4);
#pragma unroll
            for (int h = 0; h < 4; h++) {
                float t = e[h] + edv[h];
                ev[h] = (t > 0.f) ? t : 0.2f * t;
            }
        } else {
#pragma unroll
            for (int h = 0; h < 4; h++) ev[h] = -INFINITY;
        }
        // wave max per head
        f32x4 mc = ev;
#pragma unroll
        for (int o = 32; o; o >>= 1)
#pragma unroll
            for (int h = 0; h < 4; h++) mc[h] = fmaxf(mc[h], __shfl_xor(mc[h], o));
        // online-softmax update
        f32x4 al, pv;
#pragma unroll
        for (int h = 0; h < 4; h++) {
            float nm = fmaxf(m[h], mc[h]);
            al[h] = __expf(m[h] - nm);   // m=-inf on first chunk -> 0
            m[h]  = nm;
        }
#pragma unroll
        for (int h = 0; h < 4; h++) pv[h] = (l < cn) ? __expf(ev[h] - m[h]) : 0.f;
        f32x4 sc = pv;
#pragma unroll
        for (int o = 32; o; o >>= 1)
#pragma unroll
            for (int h = 0; h < 4; h++) sc[h] += __shfl_xor(sc[h], o);
#pragma unroll
        for (int h = 0; h < 4; h++) dsum[h] = dsum[h] * al[h] + sc[h];
        acc *= al[hd];
        *reinterpret_cast<f32x4*>(&p_lds[wv][l * 4]) = pv;
        // gather + FMA, 8-way unrolled (8 outstanding 8B loads per wave)
        int jm = cn & ~7;
        for (int j = 0; j < jm; j += 8) {
            s16x4 hv[8];
            float pj[8];
#pragma unroll
            for (int i = 0; i < 8; i++) {
                int sj = s_lds[wv][j + i];
                hv[i] = *reinterpret_cast<const s16x4*>(Hb + (size_t)sj * HC + l * 4);
                pj[i] = p_lds[wv][(j + i) * 4 + hd];
            }
#pragma unroll
            for (int i = 0; i < 8; i++)
#pragma unroll
                for (int k = 0; k < 4; k++) acc[k] = fmaf(pj[i], bs2f(hv[i][k]), acc[k]);
        }
        for (int j = jm; j < cn; j++) {
            int sj  = s_lds[wv][j];
            float p = p_lds[wv][j * 4 + hd];
            s16x4 hv = *reinterpret_cast<const s16x4*>(Hb + (size_t)sj * HC + l * 4);
#pragma unroll
            for (int k = 0; k < 4; k++) acc[k] = fmaf(p, bs2f(hv[k]), acc[k]);
        }
    }
    float dd = fmaxf(dsum[hd], 1e-16f);
    int bf = flag[1];
    s16x4 ov;
#pragma unroll
    for (int k = 0; k < 4; k++) {
        float v = acc[k] / dd + ldf(bias, (size_t)l * 4 + k, bf);
        ov[k] = f2bs(fmaxf(v, 0.f));
    }
    *reinterpret_cast<s16x4*>(out + (size_t)n * HC + l * 4) = ov;
}

// ---------------- readout: boundary-flush group sums (batch sorted), 250 blocks ----------------
__global__ __launch_bounds__(256) void k_groupsum(const __hip_bfloat16* __restrict__ X2,
                                                  const int* __restrict__ batch,
                                                  float* __restrict__ sx,
                                                  const int* __restrict__ flag) {
    const int RPB = NNODES / 250;  // 80
    int b = blockIdx.x, t = threadIdx.x, f = flag[0];
    int r0 = b * RPB, r1 = r0 + RPB;
    float acc = 0.f;
    int curg = ld_idx(batch, r0, f);
    for (int r = r0; r < r1; r++) {
        int g = ld_idx(batch, r, f);
        if (g != curg) { atomicAdd(&sx[(size_t)curg * HC + t], acc); acc = 0.f; curg = g; }
        acc += b2f(X2[(size_t)r * HC + t]);
    }
    atomicAdd(&sx[(size_t)curg * HC + t], acc);
}

__global__ __launch_bounds__(256) void k_final(const float* __restrict__ sx,
                                               const void* __restrict__ Wp,
                                               const void* __restrict__ bp,
                                               const int* __restrict__ batch,
                                               const int* __restrict__ flag,
                                               void* __restrict__ out) {
    int i = blockIdx.x * 256 + threadIdx.x;  // 2048 = 64*32
    int g = i >> 5, c = i & 31;
    int bf = flag[1], f = flag[0];
    int lo = 0, hi = NNODES;
    while (lo < hi) { int m = (lo + hi) >> 1; if (ld_idx(batch, m, f) < g) lo = m + 1; else hi = m; }
    int start = lo;
    hi = NNODES;
    while (lo < hi) { int m = (lo + hi) >> 1; if (ld_idx(batch, m, f) < g + 1) lo = m + 1; else hi = m; }
    int ct = lo - start;
    float acc = 0.f;
    const float* sxg = sx + (size_t)g * HC;
    for (int k = 0; k < HC; k++) acc = fmaf(sxg[k], ldf(Wp, (size_t)k * DOUT + c, bf), acc);
    float v = (ct > 0) ? (acc / ct + ldf(bp, c, bf)) : 0.f;
    if (bf) ((__hip_bfloat16*)out)[i] = __float2bfloat16(v);
    else    ((float*)out)[i] = v;
}

extern "C" void kernel_launch(void* const* d_in, const int* in_sizes, int n_in,
                              void* d_out, int out_size, void* d_ws, size_t ws_size,
                              hipStream_t stream) {
    (void)in_sizes; (void)n_in; (void)out_size; (void)ws_size;
    const void* x   = d_in[0];
    const int*  ei  = (const int*)d_in[1];
    const int*  bat = (const int*)d_in[2];
    const void* W1  = d_in[3];
    const void* as1 = d_in[4];
    const void* ad1 = d_in[5];
    const void* b1  = d_in[6];
    const void* W2  = d_in[7];
    const void* as2 = d_in[8];
    const void* ad2 = d_in[9];
    const void* b2  = d_in[10];
    const void* Wp  = d_in[11];
    const void* bp  = d_in[12];

    char* ws = (char*)d_ws;
    size_t o = 0;
    auto alloc = [&](size_t bytes) -> char* {
        char* p = ws + o;
        o += (bytes + 255) & ~(size_t)255;
        return p;
    };
    __hip_bfloat16* hb  = (__hip_bfloat16*)alloc((size_t)NNODES * HC * 2);  // bf16 h
    __hip_bfloat16* xb  = (__hip_bfloat16*)alloc((size_t)NNODES * HC * 2);  // bf16 layer-1 out
    __hip_bfloat16* xb2 = (__hip_bfloat16*)alloc((size_t)NNODES * HC * 2);  // bf16 layer-2 out
    __hip_bfloat16* Wt1 = (__hip_bfloat16*)alloc((size_t)HC * HC * 2);
    __hip_bfloat16* Wt2 = (__hip_bfloat16*)alloc((size_t)HC * HC * 2);
    float* es = (float*)alloc((size_t)NNODES * 4 * 4);
    float* ed = (float*)alloc((size_t)NNODES * 4 * 4);
    int* deg  = (int*)alloc((size_t)NNODES * 4);
    int* cur  = (int*)alloc((size_t)NNODES * 4);
    int* off  = (int*)alloc((size_t)(NNODES + 1) * 4);
    int* csr  = (int*)alloc((size_t)ETOT * 4);
    float* sx = (float*)alloc((size_t)NGROUP * HC * 4);
    int* flag = (int*)alloc(256);

    // probe + CSR (shared by both layers)
    k_probe<<<32, 256, 0, stream>>>((const unsigned int*)x, ei, flag, deg);
    k_hist<<<(ETOT + 255) / 256, 256, 0, stream>>>(ei, deg, flag);
    k_scan<<<1, 512, 0, stream>>>(deg, off, cur, sx);
    k_scatter<<<(ETOT + 255) / 256, 256, 0, stream>>>(ei, cur, csr, flag);
    k_wt<<<512, 256, 0, stream>>>(W1, W2, Wt1, Wt2, flag);

    // Layer 1
    k_gemm<<<(NNODES + 63) / 64, 256, 0, stream>>>(x, Wt1, hb, as1, ad1, es, ed, flag, 0);
    k_agg<<<NNODES / 4, 256, 0, stream>>>(hb, es, ed, b1, off, csr, flag, xb);

    // Layer 2
    k_gemm<<<(NNODES + 63) / 64, 256, 0, stream>>>(xb, Wt2, hb, as2, ad2, es, ed, flag, 1);
    k_agg<<<NNODES / 4, 256, 0, stream>>>(hb, es, ed, b2, off, csr, flag, xb2);

    // Readout
    k_groupsum<<<250, 256, 0, stream>>>(xb2, bat, sx, flag);
    k_final<<<8, 256, 0, stream>>>(sx, Wp, bp, bat, flag, d_out);
}